// Round 8
// baseline (2212.280 us; speedup 1.0000x reference)
//
#include <hip/hip_runtime.h>
#include <math.h>

// Problem dims (fixed by reference)
#define BS      256
#define FLAT    8192
#define H       1024
#define G4      4096
#define T_STEPS 64
#define AD      16
#define NOUT    16

typedef __attribute__((ext_vector_type(8))) short    bf16x8;   // MFMA A/B frag
typedef __attribute__((ext_vector_type(4))) float    f32x4;    // MFMA C/D frag
typedef __attribute__((ext_vector_type(8))) unsigned short u16x8;

__device__ __forceinline__ float sigf(float x) { return 1.0f / (1.0f + __expf(-x)); }
__device__ __forceinline__ float tanh_fast(float x) {
    float a = fabsf(x);
    float e = __expf(-2.0f * a);
    float r = (1.0f - e) / (1.0f + e);
    return copysignf(r, x);
}
__device__ __forceinline__ unsigned short f2bf(float x) {   // RNE
    unsigned int u = __float_as_uint(x);
    unsigned int r = (u + 0x7FFFu + ((u >> 16) & 1u)) >> 16;
    return (unsigned short)r;
}

// ws layout (bytes), total ~55.4 MB (ws >= 66 MB proven in round 2)
#define OFF_WRP  (1u<<20)                        // Wr packed bf16, 8 MB
#define OFF_WIP  (OFF_WRP + (8u<<20))            // Wi packed bf16, 256 KB
#define OFF_BGP  (OFF_WIP + (256u<<10))          // bg packed f32, 16 KB
#define OFF_HPA  (OFF_BGP + (16u<<10))           // h packed ping, 512 KB
#define OFF_HPB  (OFF_HPA + (512u<<10))          // h packed pong, 512 KB
#define OFF_HS   (OFF_HPB + (512u<<10))          // hs bf16 [64][256][1024], 32 MB
                                                 // (Bwp = packed Wc|Wh overlays OFF_HS:
                                                 //  consumed by init GEMM before step 0)
#define OFF_AHP  (OFF_HS + (32u<<20))            // hist packed bf16, 4 MB
#define OFF_AXP  (OFF_AHP + (4u<<20))            // action packed bf16, 1 MB
#define OFF_PART (OFF_AXP + (1u<<20))            // init split-K partials f32, 8 MB
#define OFF_WOP  (OFF_PART + (8u<<20))           // Wo packed bf16, 32 KB
#define OFF_BAR  (OFF_WOP + (64u<<10))           // global barrier counter, 64 B

// =====================================================================
// Wr pack (verified r4): Wp[nb][kc][l][i] = Wr[kc*32+(l>>4)*8+i][gatecol]
// =====================================================================
__global__ __launch_bounds__(256) void pack_wr(const float* __restrict__ Wr,
                                               unsigned short* __restrict__ Wp)
{
    int g  = blockIdx.x * 256 + threadIdx.x;     // 0..524287
    int l  = g & 63;
    int nt = (g >> 6) & 3;
    int kc = (g >> 8) & 31;
    int nb = g >> 13;
    int col   = nt * 1024 + nb * 16 + (l & 15);
    int kbase = kc * 32 + (l >> 4) * 8;
    u16x8 o;
    #pragma unroll
    for (int i = 0; i < 8; ++i)
        o[i] = f2bf(Wr[(size_t)(kbase + i) * G4 + col]);
    *(u16x8*)&Wp[(size_t)g * 8] = o;
}

// Wi pack (K zero-padded 16->32), verified r4.
__global__ __launch_bounds__(256) void pack_wi(const float* __restrict__ Wi,
                                               unsigned short* __restrict__ Wp)
{
    int g  = blockIdx.x * 256 + threadIdx.x;     // 0..16383
    int l  = g & 63;
    int nt = (g >> 6) & 3;
    int nb = g >> 8;
    int col   = nt * 1024 + nb * 16 + (l & 15);
    int kbase = (l >> 4) * 8;
    u16x8 o;
    #pragma unroll
    for (int i = 0; i < 8; ++i)
        o[i] = (kbase + i < AD) ? f2bf(Wi[(size_t)(kbase + i) * G4 + col]) : (unsigned short)0;
    *(u16x8*)&Wp[(size_t)g * 8] = o;
}

// bg pack, verified r4.
__global__ __launch_bounds__(256) void pack_bg(const float* __restrict__ bg,
                                               float* __restrict__ bgp)
{
    int t = blockIdx.x * 256 + threadIdx.x;      // 0..4095
    int jj = t & 15, nt = (t >> 4) & 3, nb = t >> 6;
    bgp[t] = bg[nt * 1024 + nb * 16 + jj];
}

// hist -> A-frag-linear bf16 (verified r6)
__global__ __launch_bounds__(256) void pack_hist(const float* __restrict__ hist,
                                                 unsigned short* __restrict__ Ap)
{
    int g  = blockIdx.x * 256 + threadIdx.x;     // grid 1024
    int l  = g & 63;
    int kc = (g >> 6) & 255;
    int mb = g >> 14;
    const float* src = hist + (size_t)(mb * 16 + (l & 15)) * FLAT + kc * 32 + (l >> 4) * 8;
    float4 v0 = *(const float4*)src;
    float4 v1 = *(const float4*)(src + 4);
    u16x8 o;
    o[0]=f2bf(v0.x); o[1]=f2bf(v0.y); o[2]=f2bf(v0.z); o[3]=f2bf(v0.w);
    o[4]=f2bf(v1.x); o[5]=f2bf(v1.y); o[6]=f2bf(v1.z); o[7]=f2bf(v1.w);
    *(u16x8*)&Ap[(size_t)g * 8] = o;
}

// Wc|Wh -> B-frag-linear bf16 (verified r6)
__global__ __launch_bounds__(256) void pack_wb(const float* __restrict__ Wc,
                                               const float* __restrict__ Wh,
                                               unsigned short* __restrict__ Bp)
{
    int g  = blockIdx.x * 256 + threadIdx.x;     // grid 8192
    int l  = g & 63;
    int kc = (g >> 6) & 255;
    int nb = g >> 14;
    const float* src = (nb & 64) ? Wh : Wc;
    int n = (nb & 63) * 16 + (l & 15);
    int k = kc * 32 + (l >> 4) * 8;
    u16x8 o;
    #pragma unroll
    for (int i = 0; i < 8; ++i)
        o[i] = f2bf(src[(size_t)(k + i) * H + n]);
    *(u16x8*)&Bp[(size_t)g * 8] = o;
}

// action -> A-frag-linear bf16, K zero-padded (verified r6)
__global__ __launch_bounds__(256) void pack_act(const float* __restrict__ act,
                                                unsigned short* __restrict__ Axp)
{
    int g = blockIdx.x * 256 + threadIdx.x;      // grid 256
    int l = g & 63;
    int q = (g >> 6) & 15;
    int t = g >> 10;
    int row = q * 16 + (l & 15);
    int kb  = (l >> 4) * 8;
    u16x8 o;
    if (kb < AD) {
        const float* src = act + ((size_t)row * T_STEPS + t) * AD + kb;
        float4 v0 = *(const float4*)src;
        float4 v1 = *(const float4*)(src + 4);
        o[0]=f2bf(v0.x); o[1]=f2bf(v0.y); o[2]=f2bf(v0.z); o[3]=f2bf(v0.w);
        o[4]=f2bf(v1.x); o[5]=f2bf(v1.y); o[6]=f2bf(v1.z); o[7]=f2bf(v1.w);
    } else {
        o = (u16x8){0,0,0,0,0,0,0,0};
    }
    *(u16x8*)&Axp[(size_t)g * 8] = o;
}

// Wo -> B-frag-linear bf16: Wop[kc][l][i] = Wo[kc*32+(l>>4)*8+i][l&15]
__global__ __launch_bounds__(256) void pack_wo(const float* __restrict__ Wo,
                                               unsigned short* __restrict__ Wop)
{
    int g = blockIdx.x * 256 + threadIdx.x;      // 0..2047 (grid 8)
    int l = g & 63;
    int kc = g >> 6;
    u16x8 o;
    #pragma unroll
    for (int i = 0; i < 8; ++i)
        o[i] = f2bf(Wo[(size_t)(kc * 32 + (l >> 4) * 8 + i) * NOUT + (l & 15)]);
    *(u16x8*)&Wop[(size_t)g * 8] = o;
}

// zero the global barrier counter (runs first, every launch)
__global__ void bar_init(unsigned int* bar) {
    if (threadIdx.x == 0 && blockIdx.x == 0) *bar = 0u;
}

// =====================================================================
// init GEMM, MFMA bf16, LDS-free, split-K x4 (verified r6)
// =====================================================================
__global__ __launch_bounds__(256) void init_gemm_mfma(
    const unsigned short* __restrict__ Ap,
    const unsigned short* __restrict__ Bp,
    float* __restrict__ part)                 // [4][256][2048]
{
    const int wg  = blockIdx.x;
    const int mb  = wg & 3;
    const int nbl = (wg >> 2) & 15;
    const int ks  = wg >> 6;
    const int tid = threadIdx.x;
    const int wv  = tid >> 6;
    const int l   = tid & 63;
    const int wm  = wv & 1;
    const int wn  = wv >> 1;

    const bf16x8* AV = (const bf16x8*)Ap;
    const bf16x8* BV = (const bf16x8*)Bp;
    const int am0 = mb * 4 + wm * 2;
    const int bn0 = nbl * 8 + wn * 4;
    const bf16x8* A0 = AV + (size_t)am0 * 16384 + l;
    const bf16x8* A1 = A0 + 16384;
    const bf16x8* B0 = BV + (size_t)bn0 * 16384 + l;
    const bf16x8* B1 = B0 + 16384;
    const bf16x8* B2 = B1 + 16384;
    const bf16x8* B3 = B2 + 16384;

    const int k0 = ks * 64;
    f32x4 acc[2][4];
    #pragma unroll
    for (int m = 0; m < 2; ++m)
        #pragma unroll
        for (int n = 0; n < 4; ++n)
            acc[m][n] = (f32x4){0.f, 0.f, 0.f, 0.f};

    bf16x8 a0 = A0[(size_t)k0 * 64], a1 = A1[(size_t)k0 * 64];
    bf16x8 b0 = B0[(size_t)k0 * 64], b1 = B1[(size_t)k0 * 64];
    bf16x8 b2 = B2[(size_t)k0 * 64], b3 = B3[(size_t)k0 * 64];

    for (int kc = k0; kc < k0 + 64; ++kc) {
        bf16x8 na0, na1, nb0, nb1, nb2, nb3;
        const bool more = (kc + 1) < k0 + 64;
        if (more) {
            size_t off = (size_t)(kc + 1) * 64;
            na0 = A0[off]; na1 = A1[off];
            nb0 = B0[off]; nb1 = B1[off]; nb2 = B2[off]; nb3 = B3[off];
        }
        acc[0][0] = __builtin_amdgcn_mfma_f32_16x16x32_bf16(a0, b0, acc[0][0], 0, 0, 0);
        acc[0][1] = __builtin_amdgcn_mfma_f32_16x16x32_bf16(a0, b1, acc[0][1], 0, 0, 0);
        acc[0][2] = __builtin_amdgcn_mfma_f32_16x16x32_bf16(a0, b2, acc[0][2], 0, 0, 0);
        acc[0][3] = __builtin_amdgcn_mfma_f32_16x16x32_bf16(a0, b3, acc[0][3], 0, 0, 0);
        acc[1][0] = __builtin_amdgcn_mfma_f32_16x16x32_bf16(a1, b0, acc[1][0], 0, 0, 0);
        acc[1][1] = __builtin_amdgcn_mfma_f32_16x16x32_bf16(a1, b1, acc[1][1], 0, 0, 0);
        acc[1][2] = __builtin_amdgcn_mfma_f32_16x16x32_bf16(a1, b2, acc[1][2], 0, 0, 0);
        acc[1][3] = __builtin_amdgcn_mfma_f32_16x16x32_bf16(a1, b3, acc[1][3], 0, 0, 0);
        if (more) { a0 = na0; a1 = na1; b0 = nb0; b1 = nb1; b2 = nb2; b3 = nb3; }
    }

    const int rbase = mb * 64 + wm * 32 + (l >> 4) * 4;
    const int cbase = nbl * 128 + wn * 64 + (l & 15);
    float* pdst = part + (size_t)ks * (BS * 2048);
    #pragma unroll
    for (int m = 0; m < 2; ++m)
        #pragma unroll
        for (int n = 0; n < 4; ++n)
            #pragma unroll
            for (int r = 0; r < 4; ++r)
                pdst[(size_t)(rbase + m * 16 + r) * 2048 + cbase + n * 16] = acc[m][n][r];
}

// reduce partials + bias + relu (verified r6)
__global__ __launch_bounds__(256) void init_reduce(
    const float* __restrict__ part,
    const float* __restrict__ bc, const float* __restrict__ bh,
    float* __restrict__ cbuf, unsigned short* __restrict__ hp0)
{
    int e = blockIdx.x * 256 + threadIdx.x;      // grid 2048
    int row = e >> 11, col = e & 2047;
    float s = (col < 1024) ? bc[col] : bh[col - 1024];
    #pragma unroll
    for (int ks = 0; ks < 4; ++ks)
        s += part[(size_t)ks * (BS * 2048) + e];
    s = fmaxf(s, 0.f);
    if (col < 1024) {
        cbuf[(size_t)row * H + col] = s;
    } else {
        int hid = col - 1024;
        int off = (row >> 6) * 65536 + (hid >> 5) * 2048 + ((row >> 4) & 3) * 512
                + ((((hid >> 3) & 3) << 4) + (row & 15)) * 8 + (hid & 7);
        hp0[off] = f2bf(s);
    }
}

// =====================================================================
// PERSISTENT LSTM scan with hand-rolled device-scope global barrier.
// Plain launch (NO cooperative API — that silently fails in this harness,
// proven r1+r7). grid 256 blocks x 256 thr, 16.5KB LDS, ~1 block/CU ->
// all blocks co-resident (1024 waves << 8192 capacity): no deadlock.
// Barrier: monotonic counter, release add + acquire spin, agent scope
// (cross-XCD visibility per G16). Body = r4/r6-verified lstm_step.
// =====================================================================
__global__ __launch_bounds__(256) void lstm_scan_persist(
    const unsigned short* __restrict__ Axp,
    const unsigned short* __restrict__ Wip,
    const unsigned short* __restrict__ Wrp,
    const float* __restrict__ bgp,
    const float* __restrict__ cbuf,           // c0 f32 (read once)
    unsigned short* __restrict__ hpA,         // ping (holds packed h0 at entry)
    unsigned short* __restrict__ hpB,         // pong
    unsigned short* __restrict__ hs,          // [64][256][1024] bf16
    unsigned int*   __restrict__ bar)         // zeroed by bar_init
{
    __shared__ __align__(16) unsigned short sB[2][4096];   // 2 x 8KB

    const int tid = threadIdx.x;
    const int wg  = blockIdx.x;
    const int mb  = wg >> 6;
    const int nb  = wg & 63;
    const int wv  = tid >> 6;
    const int l   = tid & 63;

    // persistent per-thread constants
    const int jj   = l & 15;
    const int hid  = nb * 16 + jj;
    const int rowb = mb * 64 + wv * 16 + (l >> 4) * 4;
    const int kcp  = nb >> 1;
    const int hgrp = ((nb & 1) << 1) | (jj >> 3);
    const int ii   = jj & 7;

    // c-state in registers for the whole scan
    float c_reg[4];
    #pragma unroll
    for (int r = 0; r < 4; ++r)
        c_reg[r] = cbuf[(size_t)(rowb + r) * H + hid];

    // Wi frags + bias, register-resident across all steps
    const bf16x8* WiB = ((const bf16x8*)Wip) + nb * 256;
    const bf16x8 wb0 = WiB[0 * 64 + l], wb1 = WiB[1 * 64 + l],
                 wb2 = WiB[2 * 64 + l], wb3 = WiB[3 * 64 + l];
    const float g0 = bgp[nb * 64 +  0 + jj];
    const float g1 = bgp[nb * 64 + 16 + jj];
    const float g2 = bgp[nb * 64 + 32 + jj];
    const float g3 = bgp[nb * 64 + 48 + jj];

    const u16x8* Bsrc = (const u16x8*)(Wrp + (size_t)nb * 65536);

    #pragma unroll 1
    for (int t = 0; t < T_STEPS; ++t) {
        const unsigned short* Ap = (t & 1) ? hpB : hpA;
        unsigned short*       An = (t & 1) ? hpA : hpB;
        unsigned short*       hs_t = hs + (size_t)t * (BS * H);

        // ---- B staging: chunk 0 -> LDS buf0; chunk 1 -> regs ----
        {
            u16x8 s0 = Bsrc[tid], s1 = Bsrc[256 + tid];
            *(u16x8*)&sB[0][tid * 8]         = s0;
            *(u16x8*)&sB[0][(256 + tid) * 8] = s1;
        }
        u16x8 stg0 = Bsrc[512 + tid];
        u16x8 stg1 = Bsrc[768 + tid];

        // ---- A frags: preload chunks 0 (E) and 1 (O) ----
        const bf16x8* Asrc = ((const bf16x8*)Ap) + mb * 8192 + wv * 64 + l;
        bf16x8 aE0 = Asrc[0],   aE1 = Asrc[256];
        bf16x8 aO0 = Asrc[512], aO1 = Asrc[768];

        // ---- bias init + Wi MFMA ----
        f32x4 acc[4];
        acc[0] = (f32x4){ g0, g0, g0, g0 };
        acc[1] = (f32x4){ g1, g1, g1, g1 };
        acc[2] = (f32x4){ g2, g2, g2, g2 };
        acc[3] = (f32x4){ g3, g3, g3, g3 };
        {
            bf16x8 aa = *(((const bf16x8*)Axp) + ((size_t)t * 16 + mb * 4 + wv) * 64 + l);
            acc[0] = __builtin_amdgcn_mfma_f32_16x16x32_bf16(aa, wb0, acc[0], 0, 0, 0);
            acc[1] = __builtin_amdgcn_mfma_f32_16x16x32_bf16(aa, wb1, acc[1], 0, 0, 0);
            acc[2] = __builtin_amdgcn_mfma_f32_16x16x32_bf16(aa, wb2, acc[2], 0, 0, 0);
            acc[3] = __builtin_amdgcn_mfma_f32_16x16x32_bf16(aa, wb3, acc[3], 0, 0, 0);
        }
        __syncthreads();   // sB[0] visible

        // ---- main K loop: 16 chunks of BK=64, unroll 2 ----
        #define CHUNK_BODY(C, CB, AX0, AX1)                                             \
        {                                                                               \
            bf16x8 n0, n1;                                                              \
            if ((C) < 14) { n0 = Asrc[(2*(C)+4) * 256]; n1 = Asrc[(2*(C)+5) * 256]; }   \
            bf16x8 bf00 = *(const bf16x8*)&sB[CB][(0 * 64 + l) * 8];                    \
            bf16x8 bf01 = *(const bf16x8*)&sB[CB][(1 * 64 + l) * 8];                    \
            bf16x8 bf02 = *(const bf16x8*)&sB[CB][(2 * 64 + l) * 8];                    \
            bf16x8 bf03 = *(const bf16x8*)&sB[CB][(3 * 64 + l) * 8];                    \
            bf16x8 bf10 = *(const bf16x8*)&sB[CB][(4 * 64 + l) * 8];                    \
            bf16x8 bf11 = *(const bf16x8*)&sB[CB][(5 * 64 + l) * 8];                    \
            bf16x8 bf12 = *(const bf16x8*)&sB[CB][(6 * 64 + l) * 8];                    \
            bf16x8 bf13 = *(const bf16x8*)&sB[CB][(7 * 64 + l) * 8];                    \
            if ((C) < 15) {                                                             \
                *(u16x8*)&sB[(CB) ^ 1][tid * 8]         = stg0;                         \
                *(u16x8*)&sB[(CB) ^ 1][(256 + tid) * 8] = stg1;                         \
            }                                                                           \
            if ((C) < 14) {                                                             \
                stg0 = Bsrc[((C) + 2) * 512 + tid];                                     \
                stg1 = Bsrc[((C) + 2) * 512 + 256 + tid];                               \
            }                                                                           \
            acc[0] = __builtin_amdgcn_mfma_f32_16x16x32_bf16(AX0, bf00, acc[0], 0,0,0); \
            acc[1] = __builtin_amdgcn_mfma_f32_16x16x32_bf16(AX0, bf01, acc[1], 0,0,0); \
            acc[2] = __builtin_amdgcn_mfma_f32_16x16x32_bf16(AX0, bf02, acc[2], 0,0,0); \
            acc[3] = __builtin_amdgcn_mfma_f32_16x16x32_bf16(AX0, bf03, acc[3], 0,0,0); \
            acc[0] = __builtin_amdgcn_mfma_f32_16x16x32_bf16(AX1, bf10, acc[0], 0,0,0); \
            acc[1] = __builtin_amdgcn_mfma_f32_16x16x32_bf16(AX1, bf11, acc[1], 0,0,0); \
            acc[2] = __builtin_amdgcn_mfma_f32_16x16x32_bf16(AX1, bf12, acc[2], 0,0,0); \
            acc[3] = __builtin_amdgcn_mfma_f32_16x16x32_bf16(AX1, bf13, acc[3], 0,0,0); \
            if ((C) < 14) { AX0 = n0; AX1 = n1; }                                       \
            __syncthreads();                                                            \
        }

        for (int it = 0; it < 8; ++it) {
            const int c0 = 2 * it;
            CHUNK_BODY(c0,     0, aE0, aE1)
            CHUNK_BODY(c0 + 1, 1, aO0, aO1)
        }
        #undef CHUNK_BODY

        // ---- lane-local cell update; c stays in registers ----
        #pragma unroll
        for (int r = 0; r < 4; ++r) {
            int row = rowb + r;
            float gi = acc[0][r], gf = acc[1][r], gg = acc[2][r], go = acc[3][r];
            float cv = sigf(gf) * c_reg[r] + sigf(gi) * tanh_fast(gg);
            c_reg[r] = cv;
            float hv = sigf(go) * tanh_fast(cv);
            unsigned short hb = f2bf(hv);
            hs_t[(size_t)row * H + hid] = hb;
            size_t poff = (size_t)mb * 65536 + kcp * 2048 + wv * 512
                        + (hgrp * 16 + (row & 15)) * 8 + ii;
            An[poff] = hb;
        }

        // ---- device-wide barrier (skip after last step) ----
        if (t < T_STEPS - 1) {
            __syncthreads();
            if (tid == 0) {
                __hip_atomic_fetch_add(bar, 1u, __ATOMIC_RELEASE,
                                       __HIP_MEMORY_SCOPE_AGENT);
                const unsigned int target = 256u * (unsigned int)(t + 1);
                while (__hip_atomic_load(bar, __ATOMIC_ACQUIRE,
                                         __HIP_MEMORY_SCOPE_AGENT) < target) {
                    __builtin_amdgcn_s_sleep(1);
                }
            }
            __syncthreads();
            __builtin_amdgcn_fence(__ATOMIC_ACQUIRE, "agent");  // all threads: inv caches
        }
    }
}

// =====================================================================
// out_gemm: out = hs @ Wo + bo via MFMA. M=16384 pairs, N=16, K=1024.
// grid 256 WGs x 4 waves = 1024 tiles of 16 pairs. Wo-frags LDS-staged.
// =====================================================================
__global__ __launch_bounds__(256) void out_gemm(
    const unsigned short* __restrict__ hs,   // [64][256][1024] bf16
    const unsigned short* __restrict__ Wop,  // packed Wo frags
    const float* __restrict__ bo,
    float* __restrict__ out)                 // [256][64][16]
{
    __shared__ __align__(16) unsigned short sWo[32 * 64 * 8];   // 32 KB
    const int tid = threadIdx.x;
    #pragma unroll
    for (int u = 0; u < 8; ++u) {
        int idx = u * 256 + tid;
        *(u16x8*)&sWo[idx * 8] = ((const u16x8*)Wop)[idx];
    }
    __syncthreads();

    const int wv = tid >> 6;
    const int l  = tid & 63;
    const int m  = blockIdx.x * 4 + wv;      // tile 0..1023 (pair base = m*16)
    const int b  = m >> 2;
    const int t0 = (m & 3) * 16;

    const unsigned short* Arow =
        hs + ((size_t)(t0 + (l & 15)) * BS + b) * H + (l >> 4) * 8;

    f32x4 acc = (f32x4){0.f, 0.f, 0.f, 0.f};
    bf16x8 a = *(const bf16x8*)Arow;
    for (int kc = 0; kc < 32; ++kc) {
        bf16x8 an;
        if (kc < 31) an = *(const bf16x8*)(Arow + (kc + 1) * 32);
        bf16x8 w = *(const bf16x8*)&sWo[(kc * 64 + l) * 8];
        acc = __builtin_amdgcn_mfma_f32_16x16x32_bf16(a, w, acc, 0, 0, 0);
        if (kc < 31) a = an;
    }

    const float bias = bo[l & 15];
    const int p0 = m * 16 + (l >> 4) * 4;
    #pragma unroll
    for (int r = 0; r < 4; ++r)
        out[(size_t)(p0 + r) * NOUT + (l & 15)] = acc[r] + bias;
}

// =====================================================================
extern "C" void kernel_launch(void* const* d_in, const int* in_sizes, int n_in,
                              void* d_out, int out_size, void* d_ws, size_t ws_size,
                              hipStream_t stream)
{
    const float* hist = (const float*)d_in[0];
    const float* act  = (const float*)d_in[1];
    const float* Wc   = (const float*)d_in[2];
    const float* bc   = (const float*)d_in[3];
    const float* Wh   = (const float*)d_in[4];
    const float* bh   = (const float*)d_in[5];
    const float* Wi   = (const float*)d_in[6];
    const float* Wr   = (const float*)d_in[7];
    const float* bg   = (const float*)d_in[8];
    const float* Wo   = (const float*)d_in[9];
    const float* bo   = (const float*)d_in[10];
    float* out = (float*)d_out;

    char* W = (char*)d_ws;
    float*          cbuf = (float*)W;
    unsigned short* Wrp  = (unsigned short*)(W + OFF_WRP);
    unsigned short* Wip  = (unsigned short*)(W + OFF_WIP);
    float*          bgp  = (float*)(W + OFF_BGP);
    unsigned short* hpA  = (unsigned short*)(W + OFF_HPA);
    unsigned short* hpB  = (unsigned short*)(W + OFF_HPB);
    unsigned short* hs   = (unsigned short*)(W + OFF_HS);
    unsigned short* Bwp  = (unsigned short*)(W + OFF_HS);   // overlay: consumed pre-scan
    unsigned short* Ahp  = (unsigned short*)(W + OFF_AHP);
    unsigned short* Axp  = (unsigned short*)(W + OFF_AXP);
    float*          part = (float*)(W + OFF_PART);
    unsigned short* Wop  = (unsigned short*)(W + OFF_WOP);
    unsigned int*   bar  = (unsigned int*)(W + OFF_BAR);

    bar_init <<<dim3(1),    dim3(64),  0, stream>>>(bar);
    pack_wr  <<<dim3(2048), dim3(256), 0, stream>>>(Wr, Wrp);
    pack_wi  <<<dim3(64),   dim3(256), 0, stream>>>(Wi, Wip);
    pack_bg  <<<dim3(16),   dim3(256), 0, stream>>>(bg, bgp);
    pack_hist<<<dim3(1024), dim3(256), 0, stream>>>(hist, Ahp);
    pack_wb  <<<dim3(8192), dim3(256), 0, stream>>>(Wc, Wh, Bwp);
    pack_act <<<dim3(256),  dim3(256), 0, stream>>>(act, Axp);
    pack_wo  <<<dim3(8),    dim3(256), 0, stream>>>(Wo, Wop);

    init_gemm_mfma<<<dim3(256), dim3(256), 0, stream>>>(Ahp, Bwp, part);
    init_reduce  <<<dim3(2048), dim3(256), 0, stream>>>(part, bc, bh, cbuf, hpA);

    lstm_scan_persist<<<dim3(256), dim3(256), 0, stream>>>(
        Axp, Wip, Wrp, bgp, cbuf, hpA, hpB, hs, bar);

    out_gemm<<<dim3(256), dim3(256), 0, stream>>>(hs, Wop, bo, out);
}

// Round 9
// 718.277 us; speedup vs baseline: 3.0800x; 3.0800x over previous
//
#include <hip/hip_runtime.h>
#include <math.h>

// Problem dims (fixed by reference)
#define BS      256
#define FLAT    8192
#define H       1024
#define G4      4096
#define T_STEPS 64
#define AD      16
#define NOUT    16

typedef __attribute__((ext_vector_type(8))) short    bf16x8;   // MFMA A/B frag
typedef __attribute__((ext_vector_type(4))) float    f32x4;    // MFMA C/D frag
typedef __attribute__((ext_vector_type(8))) unsigned short u16x8;

__device__ __forceinline__ float sigf(float x) { return 1.0f / (1.0f + __expf(-x)); }
__device__ __forceinline__ float tanh_fast(float x) {
    float a = fabsf(x);
    float e = __expf(-2.0f * a);
    float r = (1.0f - e) / (1.0f + e);
    return copysignf(r, x);
}
__device__ __forceinline__ unsigned short f2bf(float x) {   // RNE
    unsigned int u = __float_as_uint(x);
    unsigned int r = (u + 0x7FFFu + ((u >> 16) & 1u)) >> 16;
    return (unsigned short)r;
}

// ws layout (bytes), peak footprint 56 MB (< 66 MB proven in round 2)
#define OFF_WRP  (1u<<20)                        // Wr packed bf16, 8 MB
#define OFF_WIP  (OFF_WRP + (8u<<20))            // Wi packed bf16, 256 KB
#define OFF_BGP  (OFF_WIP + (256u<<10))          // bg packed f32, 16 KB
#define OFF_WOP  (OFF_BGP + (16u<<10))           // Wo packed bf16, 32 KB
#define OFF_BAR  (OFF_WOP + (32u<<10))           // barrier counter, 64 B
#define OFF_AXP  (10u<<20)                       // action packed bf16, 1 MB
#define OFF_HALL (11u<<20)                       // h_all: 65 x 512 KB = 32.5 MB
                                                 //  h_all[0]=h0; h_all[t+1]=h after step t
                                                 //  (Bwp 32 MB overlays h_all: init-only)
#define OFF_AHP  (44u<<20)                       // hist packed bf16, 4 MB (init-only)
#define OFF_PART (48u<<20)                       // init split-K partials f32, 8 MB (init-only)

#define HALL_STRIDE 262144u                      // u16 elems per h_all buffer (512 KB)

// =====================================================================
// Wr pack (verified r4): Wp[nb][kc][l][i] = Wr[kc*32+(l>>4)*8+i][gatecol]
// =====================================================================
__global__ __launch_bounds__(256) void pack_wr(const float* __restrict__ Wr,
                                               unsigned short* __restrict__ Wp)
{
    int g  = blockIdx.x * 256 + threadIdx.x;     // 0..524287
    int l  = g & 63;
    int nt = (g >> 6) & 3;
    int kc = (g >> 8) & 31;
    int nb = g >> 13;
    int col   = nt * 1024 + nb * 16 + (l & 15);
    int kbase = kc * 32 + (l >> 4) * 8;
    u16x8 o;
    #pragma unroll
    for (int i = 0; i < 8; ++i)
        o[i] = f2bf(Wr[(size_t)(kbase + i) * G4 + col]);
    *(u16x8*)&Wp[(size_t)g * 8] = o;
}

// Wi pack (K zero-padded 16->32), verified r4.
__global__ __launch_bounds__(256) void pack_wi(const float* __restrict__ Wi,
                                               unsigned short* __restrict__ Wp)
{
    int g  = blockIdx.x * 256 + threadIdx.x;     // 0..16383
    int l  = g & 63;
    int nt = (g >> 6) & 3;
    int nb = g >> 8;
    int col   = nt * 1024 + nb * 16 + (l & 15);
    int kbase = (l >> 4) * 8;
    u16x8 o;
    #pragma unroll
    for (int i = 0; i < 8; ++i)
        o[i] = (kbase + i < AD) ? f2bf(Wi[(size_t)(kbase + i) * G4 + col]) : (unsigned short)0;
    *(u16x8*)&Wp[(size_t)g * 8] = o;
}

// bg pack, verified r4.
__global__ __launch_bounds__(256) void pack_bg(const float* __restrict__ bg,
                                               float* __restrict__ bgp)
{
    int t = blockIdx.x * 256 + threadIdx.x;      // 0..4095
    int jj = t & 15, nt = (t >> 4) & 3, nb = t >> 6;
    bgp[t] = bg[nt * 1024 + nb * 16 + jj];
}

// hist -> A-frag-linear bf16 (verified r6)
__global__ __launch_bounds__(256) void pack_hist(const float* __restrict__ hist,
                                                 unsigned short* __restrict__ Ap)
{
    int g  = blockIdx.x * 256 + threadIdx.x;     // grid 1024
    int l  = g & 63;
    int kc = (g >> 6) & 255;
    int mb = g >> 14;
    const float* src = hist + (size_t)(mb * 16 + (l & 15)) * FLAT + kc * 32 + (l >> 4) * 8;
    float4 v0 = *(const float4*)src;
    float4 v1 = *(const float4*)(src + 4);
    u16x8 o;
    o[0]=f2bf(v0.x); o[1]=f2bf(v0.y); o[2]=f2bf(v0.z); o[3]=f2bf(v0.w);
    o[4]=f2bf(v1.x); o[5]=f2bf(v1.y); o[6]=f2bf(v1.z); o[7]=f2bf(v1.w);
    *(u16x8*)&Ap[(size_t)g * 8] = o;
}

// Wc|Wh -> B-frag-linear bf16 (verified r6)
__global__ __launch_bounds__(256) void pack_wb(const float* __restrict__ Wc,
                                               const float* __restrict__ Wh,
                                               unsigned short* __restrict__ Bp)
{
    int g  = blockIdx.x * 256 + threadIdx.x;     // grid 8192
    int l  = g & 63;
    int kc = (g >> 6) & 255;
    int nb = g >> 14;
    const float* src = (nb & 64) ? Wh : Wc;
    int n = (nb & 63) * 16 + (l & 15);
    int k = kc * 32 + (l >> 4) * 8;
    u16x8 o;
    #pragma unroll
    for (int i = 0; i < 8; ++i)
        o[i] = f2bf(src[(size_t)(k + i) * H + n]);
    *(u16x8*)&Bp[(size_t)g * 8] = o;
}

// action -> A-frag-linear bf16, K zero-padded (verified r6)
__global__ __launch_bounds__(256) void pack_act(const float* __restrict__ act,
                                                unsigned short* __restrict__ Axp)
{
    int g = blockIdx.x * 256 + threadIdx.x;      // grid 256
    int l = g & 63;
    int q = (g >> 6) & 15;
    int t = g >> 10;
    int row = q * 16 + (l & 15);
    int kb  = (l >> 4) * 8;
    u16x8 o;
    if (kb < AD) {
        const float* src = act + ((size_t)row * T_STEPS + t) * AD + kb;
        float4 v0 = *(const float4*)src;
        float4 v1 = *(const float4*)(src + 4);
        o[0]=f2bf(v0.x); o[1]=f2bf(v0.y); o[2]=f2bf(v0.z); o[3]=f2bf(v0.w);
        o[4]=f2bf(v1.x); o[5]=f2bf(v1.y); o[6]=f2bf(v1.z); o[7]=f2bf(v1.w);
    } else {
        o = (u16x8){0,0,0,0,0,0,0,0};
    }
    *(u16x8*)&Axp[(size_t)g * 8] = o;
}

// Wo -> B-frag-linear bf16 (ran in r8): Wop[kc][l][i] = Wo[kc*32+(l>>4)*8+i][l&15]
__global__ __launch_bounds__(256) void pack_wo(const float* __restrict__ Wo,
                                               unsigned short* __restrict__ Wop)
{
    int g = blockIdx.x * 256 + threadIdx.x;      // 0..2047 (grid 8)
    int l = g & 63;
    int kc = g >> 6;
    u16x8 o;
    #pragma unroll
    for (int i = 0; i < 8; ++i)
        o[i] = f2bf(Wo[(size_t)(kc * 32 + (l >> 4) * 8 + i) * NOUT + (l & 15)]);
    *(u16x8*)&Wop[(size_t)g * 8] = o;
}

// zero the global barrier counter (runs first, every launch)
__global__ void bar_init(unsigned int* bar) {
    if (threadIdx.x == 0 && blockIdx.x == 0) *bar = 0u;
}

// =====================================================================
// init GEMM, MFMA bf16, LDS-free, split-K x4 (verified r6)
// =====================================================================
__global__ __launch_bounds__(256) void init_gemm_mfma(
    const unsigned short* __restrict__ Ap,
    const unsigned short* __restrict__ Bp,
    float* __restrict__ part)                 // [4][256][2048]
{
    const int wg  = blockIdx.x;
    const int mb  = wg & 3;
    const int nbl = (wg >> 2) & 15;
    const int ks  = wg >> 6;
    const int tid = threadIdx.x;
    const int wv  = tid >> 6;
    const int l   = tid & 63;
    const int wm  = wv & 1;
    const int wn  = wv >> 1;

    const bf16x8* AV = (const bf16x8*)Ap;
    const bf16x8* BV = (const bf16x8*)Bp;
    const int am0 = mb * 4 + wm * 2;
    const int bn0 = nbl * 8 + wn * 4;
    const bf16x8* A0 = AV + (size_t)am0 * 16384 + l;
    const bf16x8* A1 = A0 + 16384;
    const bf16x8* B0 = BV + (size_t)bn0 * 16384 + l;
    const bf16x8* B1 = B0 + 16384;
    const bf16x8* B2 = B1 + 16384;
    const bf16x8* B3 = B2 + 16384;

    const int k0 = ks * 64;
    f32x4 acc[2][4];
    #pragma unroll
    for (int m = 0; m < 2; ++m)
        #pragma unroll
        for (int n = 0; n < 4; ++n)
            acc[m][n] = (f32x4){0.f, 0.f, 0.f, 0.f};

    bf16x8 a0 = A0[(size_t)k0 * 64], a1 = A1[(size_t)k0 * 64];
    bf16x8 b0 = B0[(size_t)k0 * 64], b1 = B1[(size_t)k0 * 64];
    bf16x8 b2 = B2[(size_t)k0 * 64], b3 = B3[(size_t)k0 * 64];

    for (int kc = k0; kc < k0 + 64; ++kc) {
        bf16x8 na0, na1, nb0, nb1, nb2, nb3;
        const bool more = (kc + 1) < k0 + 64;
        if (more) {
            size_t off = (size_t)(kc + 1) * 64;
            na0 = A0[off]; na1 = A1[off];
            nb0 = B0[off]; nb1 = B1[off]; nb2 = B2[off]; nb3 = B3[off];
        }
        acc[0][0] = __builtin_amdgcn_mfma_f32_16x16x32_bf16(a0, b0, acc[0][0], 0, 0, 0);
        acc[0][1] = __builtin_amdgcn_mfma_f32_16x16x32_bf16(a0, b1, acc[0][1], 0, 0, 0);
        acc[0][2] = __builtin_amdgcn_mfma_f32_16x16x32_bf16(a0, b2, acc[0][2], 0, 0, 0);
        acc[0][3] = __builtin_amdgcn_mfma_f32_16x16x32_bf16(a0, b3, acc[0][3], 0, 0, 0);
        acc[1][0] = __builtin_amdgcn_mfma_f32_16x16x32_bf16(a1, b0, acc[1][0], 0, 0, 0);
        acc[1][1] = __builtin_amdgcn_mfma_f32_16x16x32_bf16(a1, b1, acc[1][1], 0, 0, 0);
        acc[1][2] = __builtin_amdgcn_mfma_f32_16x16x32_bf16(a1, b2, acc[1][2], 0, 0, 0);
        acc[1][3] = __builtin_amdgcn_mfma_f32_16x16x32_bf16(a1, b3, acc[1][3], 0, 0, 0);
        if (more) { a0 = na0; a1 = na1; b0 = nb0; b1 = nb1; b2 = nb2; b3 = nb3; }
    }

    const int rbase = mb * 64 + wm * 32 + (l >> 4) * 4;
    const int cbase = nbl * 128 + wn * 64 + (l & 15);
    float* pdst = part + (size_t)ks * (BS * 2048);
    #pragma unroll
    for (int m = 0; m < 2; ++m)
        #pragma unroll
        for (int n = 0; n < 4; ++n)
            #pragma unroll
            for (int r = 0; r < 4; ++r)
                pdst[(size_t)(rbase + m * 16 + r) * 2048 + cbase + n * 16] = acc[m][n][r];
}

// reduce partials + bias + relu (verified r6); h0 -> h_all[0] packed
__global__ __launch_bounds__(256) void init_reduce(
    const float* __restrict__ part,
    const float* __restrict__ bc, const float* __restrict__ bh,
    float* __restrict__ cbuf, unsigned short* __restrict__ hp0)
{
    int e = blockIdx.x * 256 + threadIdx.x;      // grid 2048
    int row = e >> 11, col = e & 2047;
    float s = (col < 1024) ? bc[col] : bh[col - 1024];
    #pragma unroll
    for (int ks = 0; ks < 4; ++ks)
        s += part[(size_t)ks * (BS * 2048) + e];
    s = fmaxf(s, 0.f);
    if (col < 1024) {
        cbuf[(size_t)row * H + col] = s;
    } else {
        int hid = col - 1024;
        int off = (row >> 6) * 65536 + (hid >> 5) * 2048 + ((row >> 4) & 3) * 512
                + ((((hid >> 3) & 3) << 4) + (row & 15)) * 8 + (hid & 7);
        hp0[off] = f2bf(s);
    }
}

// =====================================================================
// PERSISTENT LSTM scan, NO cache-wide fences (r8's fences caused the
// 31us/step stall: acquire=full-L2-inv nuked the Wr cache every step).
// Coherence recipe:
//  - h writes: relaxed agent-scope u32 atomic stores (write-through to
//    L3, no L2 allocation) into step-indexed h_all[t+1] (write-once).
//  - h reads: PLAIN cached loads — safe because each h_all buffer's
//    lines were never cached anywhere before the barrier that orders
//    write -> read (write-once-then-read), so no stale line can exist.
//  - Wr/Wi/Axp: plain cached reads, stay L2-hot across all 64 steps.
//  - barrier: r8-proven monotonic counter, all-relaxed. __syncthreads
//    drains vmcnt (compiler emits s_waitcnt vmcnt(0) before s_barrier)
//    so sc1 h-stores are in L3 before the counter add is visible.
// grid 256 = mb(4) x nb(64); block 256 = 4 waves; c-state in registers.
// =====================================================================
__global__ __launch_bounds__(256) void lstm_scan_persist(
    const unsigned short* __restrict__ Axp,
    const unsigned short* __restrict__ Wip,
    const unsigned short* __restrict__ Wrp,
    const float* __restrict__ bgp,
    const float* __restrict__ cbuf,           // c0 f32 (read once)
    unsigned short* __restrict__ hall,        // h_all[65][HALL_STRIDE]
    unsigned int*   __restrict__ bar)         // zeroed by bar_init
{
    __shared__ __align__(16) unsigned short sB[2][4096];   // 2 x 8KB

    const int tid = threadIdx.x;
    const int wg  = blockIdx.x;
    const int mb  = wg >> 6;
    const int nb  = wg & 63;
    const int wv  = tid >> 6;
    const int l   = tid & 63;

    // persistent per-thread constants
    const int jj   = l & 15;
    const int hid  = nb * 16 + jj;
    const int rowb = mb * 64 + wv * 16 + (l >> 4) * 4;
    const int kcp  = nb >> 1;
    const int hgrp = ((nb & 1) << 1) | (jj >> 3);
    const int ii   = jj & 7;
    // packed u16 offset base for (row, hid): + (row&15)*8 added per r
    const int pbase = mb * 65536 + kcp * 2048 + wv * 512 + hgrp * 128 + ii;

    // c-state in registers for the whole scan
    float c_reg[4];
    #pragma unroll
    for (int r = 0; r < 4; ++r)
        c_reg[r] = cbuf[(size_t)(rowb + r) * H + hid];

    // Wi frags + bias, register-resident across all steps
    const bf16x8* WiB = ((const bf16x8*)Wip) + nb * 256;
    const bf16x8 wb0 = WiB[0 * 64 + l], wb1 = WiB[1 * 64 + l],
                 wb2 = WiB[2 * 64 + l], wb3 = WiB[3 * 64 + l];
    const float g0 = bgp[nb * 64 +  0 + jj];
    const float g1 = bgp[nb * 64 + 16 + jj];
    const float g2 = bgp[nb * 64 + 32 + jj];
    const float g3 = bgp[nb * 64 + 48 + jj];

    const u16x8* Bsrc = (const u16x8*)(Wrp + (size_t)nb * 65536);

    #pragma unroll 1
    for (int t = 0; t < T_STEPS; ++t) {
        const unsigned short* Ap = hall + (size_t)t * HALL_STRIDE;
        unsigned int* An32 = (unsigned int*)(hall + (size_t)(t + 1) * HALL_STRIDE);

        // ---- B staging: chunk 0 -> LDS buf0; chunk 1 -> regs ----
        {
            u16x8 s0 = Bsrc[tid], s1 = Bsrc[256 + tid];
            *(u16x8*)&sB[0][tid * 8]         = s0;
            *(u16x8*)&sB[0][(256 + tid) * 8] = s1;
        }
        u16x8 stg0 = Bsrc[512 + tid];
        u16x8 stg1 = Bsrc[768 + tid];

        // ---- A frags: preload chunks 0 (E) and 1 (O), plain cached ----
        const bf16x8* Asrc = ((const bf16x8*)Ap) + mb * 8192 + wv * 64 + l;
        bf16x8 aE0 = Asrc[0],   aE1 = Asrc[256];
        bf16x8 aO0 = Asrc[512], aO1 = Asrc[768];

        // ---- bias init + Wi MFMA ----
        f32x4 acc[4];
        acc[0] = (f32x4){ g0, g0, g0, g0 };
        acc[1] = (f32x4){ g1, g1, g1, g1 };
        acc[2] = (f32x4){ g2, g2, g2, g2 };
        acc[3] = (f32x4){ g3, g3, g3, g3 };
        {
            bf16x8 aa = *(((const bf16x8*)Axp) + ((size_t)t * 16 + mb * 4 + wv) * 64 + l);
            acc[0] = __builtin_amdgcn_mfma_f32_16x16x32_bf16(aa, wb0, acc[0], 0, 0, 0);
            acc[1] = __builtin_amdgcn_mfma_f32_16x16x32_bf16(aa, wb1, acc[1], 0, 0, 0);
            acc[2] = __builtin_amdgcn_mfma_f32_16x16x32_bf16(aa, wb2, acc[2], 0, 0, 0);
            acc[3] = __builtin_amdgcn_mfma_f32_16x16x32_bf16(aa, wb3, acc[3], 0, 0, 0);
        }
        __syncthreads();   // sB[0] visible

        // ---- main K loop: 16 chunks of BK=64, unroll 2 ----
        #define CHUNK_BODY(C, CB, AX0, AX1)                                             \
        {                                                                               \
            bf16x8 n0, n1;                                                              \
            if ((C) < 14) { n0 = Asrc[(2*(C)+4) * 256]; n1 = Asrc[(2*(C)+5) * 256]; }   \
            bf16x8 bf00 = *(const bf16x8*)&sB[CB][(0 * 64 + l) * 8];                    \
            bf16x8 bf01 = *(const bf16x8*)&sB[CB][(1 * 64 + l) * 8];                    \
            bf16x8 bf02 = *(const bf16x8*)&sB[CB][(2 * 64 + l) * 8];                    \
            bf16x8 bf03 = *(const bf16x8*)&sB[CB][(3 * 64 + l) * 8];                    \
            bf16x8 bf10 = *(const bf16x8*)&sB[CB][(4 * 64 + l) * 8];                    \
            bf16x8 bf11 = *(const bf16x8*)&sB[CB][(5 * 64 + l) * 8];                    \
            bf16x8 bf12 = *(const bf16x8*)&sB[CB][(6 * 64 + l) * 8];                    \
            bf16x8 bf13 = *(const bf16x8*)&sB[CB][(7 * 64 + l) * 8];                    \
            if ((C) < 15) {                                                             \
                *(u16x8*)&sB[(CB) ^ 1][tid * 8]         = stg0;                         \
                *(u16x8*)&sB[(CB) ^ 1][(256 + tid) * 8] = stg1;                         \
            }                                                                           \
            if ((C) < 14) {                                                             \
                stg0 = Bsrc[((C) + 2) * 512 + tid];                                     \
                stg1 = Bsrc[((C) + 2) * 512 + 256 + tid];                               \
            }                                                                           \
            acc[0] = __builtin_amdgcn_mfma_f32_16x16x32_bf16(AX0, bf00, acc[0], 0,0,0); \
            acc[1] = __builtin_amdgcn_mfma_f32_16x16x32_bf16(AX0, bf01, acc[1], 0,0,0); \
            acc[2] = __builtin_amdgcn_mfma_f32_16x16x32_bf16(AX0, bf02, acc[2], 0,0,0); \
            acc[3] = __builtin_amdgcn_mfma_f32_16x16x32_bf16(AX0, bf03, acc[3], 0,0,0); \
            acc[0] = __builtin_amdgcn_mfma_f32_16x16x32_bf16(AX1, bf10, acc[0], 0,0,0); \
            acc[1] = __builtin_amdgcn_mfma_f32_16x16x32_bf16(AX1, bf11, acc[1], 0,0,0); \
            acc[2] = __builtin_amdgcn_mfma_f32_16x16x32_bf16(AX1, bf12, acc[2], 0,0,0); \
            acc[3] = __builtin_amdgcn_mfma_f32_16x16x32_bf16(AX1, bf13, acc[3], 0,0,0); \
            if ((C) < 14) { AX0 = n0; AX1 = n1; }                                       \
            __syncthreads();                                                            \
        }

        for (int it = 0; it < 8; ++it) {
            const int c0 = 2 * it;
            CHUNK_BODY(c0,     0, aE0, aE1)
            CHUNK_BODY(c0 + 1, 1, aO0, aO1)
        }
        #undef CHUNK_BODY

        // ---- lane-local cell update; c in registers; h -> h_all[t+1]
        //      as write-through u32 atomics (pair lanes jj, jj^1) ----
        #pragma unroll
        for (int r = 0; r < 4; ++r) {
            float gi = acc[0][r], gf = acc[1][r], gg = acc[2][r], go = acc[3][r];
            float cv = sigf(gf) * c_reg[r] + sigf(gi) * tanh_fast(gg);
            c_reg[r] = cv;
            float hv = sigf(go) * tanh_fast(cv);
            unsigned int hb = (unsigned int)f2bf(hv);
            unsigned int pb = (unsigned int)__shfl_xor((int)hb, 1, 64) & 0xFFFFu;
            if ((jj & 1) == 0) {
                unsigned int val = (hb & 0xFFFFu) | (pb << 16);
                int poff = pbase + (((l >> 4) * 4 + r) << 3);   // + (row&15)*8
                __hip_atomic_store(&An32[poff >> 1], val,
                                   __ATOMIC_RELAXED, __HIP_MEMORY_SCOPE_AGENT);
            }
        }

        // ---- device-wide barrier, all-relaxed (skip after last step) ----
        if (t < T_STEPS - 1) {
            __syncthreads();   // drains vmcnt(0): sc1 h-stores reached L3
            if (tid == 0) {
                __hip_atomic_fetch_add(bar, 1u, __ATOMIC_RELAXED,
                                       __HIP_MEMORY_SCOPE_AGENT);
                const unsigned int target = 256u * (unsigned int)(t + 1);
                while (__hip_atomic_load(bar, __ATOMIC_RELAXED,
                                         __HIP_MEMORY_SCOPE_AGENT) < target) {
                    __builtin_amdgcn_s_sleep(2);
                }
            }
            __syncthreads();
        }
    }
}

// =====================================================================
// out_gemm v2: out[b][t][:] = h_all[t+1] @ Wo + bo via MFMA, reading
// A-frags straight from the packed h_all layout (same frag algebra as
// the scan: frag idx = mb*8192 + kc*256 + wv*64 + l, mb=rt>>2, wv=rt&3).
// grid 256 x 4 waves = 1024 = t(64) x rowtile(16 of 16 batches).
// =====================================================================
__global__ __launch_bounds__(256) void out_gemm(
    const unsigned short* __restrict__ hall, // h_all[65][HALL_STRIDE]
    const unsigned short* __restrict__ Wop,  // packed Wo frags
    const float* __restrict__ bo,
    float* __restrict__ out)                 // [256][64][16]
{
    __shared__ __align__(16) unsigned short sWo[32 * 64 * 8];   // 32 KB
    const int tid = threadIdx.x;
    #pragma unroll
    for (int u = 0; u < 8; ++u) {
        int idx = u * 256 + tid;
        *(u16x8*)&sWo[idx * 8] = ((const u16x8*)Wop)[idx];
    }
    __syncthreads();

    const int wv  = tid >> 6;
    const int l   = tid & 63;
    const int gid = blockIdx.x * 4 + wv;     // 0..1023
    const int t   = gid >> 4;                // output timestep
    const int rt  = gid & 15;                // row-tile: batches rt*16..+15

    const bf16x8* Asrc = ((const bf16x8*)(hall + (size_t)(t + 1) * HALL_STRIDE))
                       + (rt >> 2) * 8192 + (rt & 3) * 64 + l;

    f32x4 acc = (f32x4){0.f, 0.f, 0.f, 0.f};
    bf16x8 a = Asrc[0];
    for (int kc = 0; kc < 32; ++kc) {
        bf16x8 an;
        if (kc < 31) an = Asrc[(kc + 1) * 256];
        bf16x8 w = *(const bf16x8*)&sWo[(kc * 64 + l) * 8];
        acc = __builtin_amdgcn_mfma_f32_16x16x32_bf16(a, w, acc, 0, 0, 0);
        if (kc < 31) a = an;
    }

    const float bias = bo[l & 15];
    #pragma unroll
    for (int r = 0; r < 4; ++r) {
        int b = rt * 16 + (l >> 4) * 4 + r;  // C layout: row=(l>>4)*4+r
        out[((size_t)b * T_STEPS + t) * NOUT + (l & 15)] = acc[r] + bias;
    }
}

// =====================================================================
extern "C" void kernel_launch(void* const* d_in, const int* in_sizes, int n_in,
                              void* d_out, int out_size, void* d_ws, size_t ws_size,
                              hipStream_t stream)
{
    const float* hist = (const float*)d_in[0];
    const float* act  = (const float*)d_in[1];
    const float* Wc   = (const float*)d_in[2];
    const float* bc   = (const float*)d_in[3];
    const float* Wh   = (const float*)d_in[4];
    const float* bh   = (const float*)d_in[5];
    const float* Wi   = (const float*)d_in[6];
    const float* Wr   = (const float*)d_in[7];
    const float* bg   = (const float*)d_in[8];
    const float* Wo   = (const float*)d_in[9];
    const float* bo   = (const float*)d_in[10];
    float* out = (float*)d_out;

    char* W = (char*)d_ws;
    float*          cbuf = (float*)W;
    unsigned short* Wrp  = (unsigned short*)(W + OFF_WRP);
    unsigned short* Wip  = (unsigned short*)(W + OFF_WIP);
    float*          bgp  = (float*)(W + OFF_BGP);
    unsigned short* Wop  = (unsigned short*)(W + OFF_WOP);
    unsigned int*   bar  = (unsigned int*)(W + OFF_BAR);
    unsigned short* Axp  = (unsigned short*)(W + OFF_AXP);
    unsigned short* hall = (unsigned short*)(W + OFF_HALL);
    unsigned short* Bwp  = (unsigned short*)(W + OFF_HALL);  // init-only overlay
    unsigned short* Ahp  = (unsigned short*)(W + OFF_AHP);
    float*          part = (float*)(W + OFF_PART);

    bar_init <<<dim3(1),    dim3(64),  0, stream>>>(bar);
    pack_wr  <<<dim3(2048), dim3(256), 0, stream>>>(Wr, Wrp);
    pack_wi  <<<dim3(64),   dim3(256), 0, stream>>>(Wi, Wip);
    pack_bg  <<<dim3(16),   dim3(256), 0, stream>>>(bg, bgp);
    pack_hist<<<dim3(1024), dim3(256), 0, stream>>>(hist, Ahp);
    pack_wb  <<<dim3(8192), dim3(256), 0, stream>>>(Wc, Wh, Bwp);
    pack_act <<<dim3(256),  dim3(256), 0, stream>>>(act, Axp);
    pack_wo  <<<dim3(8),    dim3(256), 0, stream>>>(Wo, Wop);

    init_gemm_mfma<<<dim3(256), dim3(256), 0, stream>>>(Ahp, Bwp, part);
    init_reduce  <<<dim3(2048), dim3(256), 0, stream>>>(part, bc, bh, cbuf, hall);

    lstm_scan_persist<<<dim3(256), dim3(256), 0, stream>>>(
        Axp, Wip, Wrp, bgp, cbuf, hall, bar);

    out_gemm<<<dim3(256), dim3(256), 0, stream>>>(hall, Wop, bo, out);
}